// Round 11
// baseline (264.390 us; speedup 1.0000x reference)
//
#include <hip/hip_runtime.h>

#define Hd 128
#define LDA 136     // LDS leading dim (bf16 elems)
#define ZW 1152     // z row width (bf16): [root | 8 rels] * 128
#define ZW2 576     // z row width in uints
#define MAXDEG 64   // padded edge slots per dst node

typedef __attribute__((ext_vector_type(8))) short short8;   // 8 bf16 = 4 VGPRs
typedef __attribute__((ext_vector_type(4))) float f32x4;
typedef __attribute__((ext_vector_type(4))) unsigned int u32x4;

__device__ __forceinline__ unsigned short f2bf(float f) {
    union { float f; unsigned u; } v; v.f = f;
    unsigned r = v.u + 0x7FFFu + ((v.u >> 16) & 1u);   // RNE
    return (unsigned short)(r >> 16);
}

// ---------- merged prep: [0,18) weight transpose (+K-perm for layer-2),
// [18,..) edge placement into padded slots + outmask (no CSR, no scan, no cvt pass) ----------
__global__ __launch_bounds__(256) void prep_kernel(const float* __restrict__ root1,
                                                   const float* __restrict__ W1,
                                                   const float* __restrict__ root2,
                                                   const float* __restrict__ W2,
                                                   unsigned short* __restrict__ Bt,
                                                   const int* __restrict__ src,
                                                   const int* __restrict__ dstp,
                                                   const int* __restrict__ et, int E,
                                                   int* __restrict__ deg,
                                                   int* __restrict__ outmask,
                                                   unsigned int* __restrict__ epk,
                                                   unsigned long long* __restrict__ ovf,
                                                   int* __restrict__ ovfc) {
    const int tid = threadIdx.x;
    if (blockIdx.x < 18) {
        // Bt[b][n*128 + kp] = bf16(W[k][n]); kp = perm(k) for b>=9 (layer-2 K matches permuted h)
        __shared__ float S[32 * 129];
        const int b = blockIdx.x;
        const float* Ws;
        if (b == 0)       Ws = root1;
        else if (b < 9)   Ws = W1 + (size_t)(b - 1) * 16384;
        else if (b == 9)  Ws = root2;
        else              Ws = W2 + (size_t)(b - 10) * 16384;
        unsigned short* Bd = Bt + (size_t)b * 16384;
        for (int s = 0; s < 4; ++s) {
            __syncthreads();
#pragma unroll
            for (int i = 0; i < 16; ++i) {     // load rows k in [32s,32s+32)
                int idx = i * 256 + tid;
                int k = idx >> 7, n = idx & 127;
                S[k * 129 + n] = Ws[(size_t)(32 * s + k) * 128 + n];
            }
            __syncthreads();
#pragma unroll
            for (int i = 0; i < 16; ++i) {     // write Bd[n][kp]
                int idx = i * 256 + tid;
                int n = idx >> 5, kk = idx & 31;
                int k = 32 * s + kk;
                int kp = (b >= 9) ? (((k & 15) << 3) | (k >> 4)) : k;
                Bd[n * 128 + kp] = f2bf(S[kk * 129 + n]);
            }
        }
    } else {
        // edge placement: epk[dst*64 + idx] = src*8 + rel; outmask[src] |= 1<<rel
        int e = (blockIdx.x - 18) * 256 + tid;
        if (e < E) {
            int r = et[e];
            int d = dstp[e];
            int s = src[e];
            int idx = atomicAdd(&deg[d], 1);
            atomicOr(&outmask[s], 1 << r);
            unsigned pay = ((unsigned)s << 3) | (unsigned)r;
            if (idx < MAXDEG) epk[(size_t)d * MAXDEG + idx] = pay;
            else {
                int o = atomicAdd(ovfc, 1);
                ovf[o] = ((unsigned long long)(unsigned)d << 32) | pay;
            }
        }
    }
}

// ---------- dense GEMM: z[:, ct-block] = A @ Bt[ct]; split-B (3 blocks/CU); outmask store-skip ----------
// A source: Af32 (fp32, inline cvt) if non-null, else Abf (bf16).  z phys col order: p=(c&15)*8+(c>>4)
__global__ __launch_bounds__(256, 3) void gemm_z(const unsigned short* __restrict__ Abf,
                                                 const float* __restrict__ Af32,
                                                 const unsigned short* __restrict__ Bt9,
                                                 const int* __restrict__ outmask,
                                                 unsigned short* __restrict__ z, int M) {
    __shared__ __align__(16) unsigned short As[128 * LDA];   // 34816 B
    __shared__ __align__(16) unsigned short Bs[64 * LDA];    // 17408 B
    const int tid = threadIdx.x;

    // bijective XCD swizzle: same-mtile blocks land on one XCD -> A-tile L2 reuse
    const int nwg = gridDim.x;
    const int nq = nwg >> 3, rr = nwg & 7;
    const int xcd = blockIdx.x & 7, bix = blockIdx.x >> 3;
    const int swz = (xcd < rr ? xcd * (nq + 1) : rr * (nq + 1) + (xcd - rr) * nq) + bix;
    const int mtile = swz / 9, ctile = swz % 9;

    const int rowBase = mtile * 128;
    const int wave = tid >> 6, lane = tid & 63;
    const int lm = lane & 15, lk = (lane >> 4) * 8;
    const unsigned short* Btt = Bt9 + (size_t)ctile * 16384;

    // stage A-tile (full) + B half 0 (rows 0..63)
    if (Af32) {
#pragma unroll
        for (int i = 0; i < 8; ++i) {
            int idx = i * 256 + tid;
            int r = idx >> 4, c16 = idx & 15;
            int grow = rowBase + r; if (grow >= M) grow = M - 1;
            const float4* px = (const float4*)&Af32[(size_t)grow * Hd + c16 * 8];
            float4 v0 = px[0], v1 = px[1];
            ushort4 o0, o1;
            o0.x = f2bf(v0.x); o0.y = f2bf(v0.y); o0.z = f2bf(v0.z); o0.w = f2bf(v0.w);
            o1.x = f2bf(v1.x); o1.y = f2bf(v1.y); o1.z = f2bf(v1.z); o1.w = f2bf(v1.w);
            *(ushort4*)&As[r * LDA + c16 * 8]     = o0;
            *(ushort4*)&As[r * LDA + c16 * 8 + 4] = o1;
        }
    } else {
#pragma unroll
        for (int i = 0; i < 8; ++i) {
            int idx = i * 256 + tid;
            int r = idx >> 4, c16 = idx & 15;
            int grow = rowBase + r; if (grow >= M) grow = M - 1;
            *(float4*)&As[r * LDA + c16 * 8] = *(const float4*)&Abf[(size_t)grow * Hd + c16 * 8];
        }
    }
#pragma unroll
    for (int i = 0; i < 4; ++i) {
        int idx = i * 256 + tid;             // 0..1023 = 64 rows x 16 float4
        *(float4*)&Bs[(idx >> 4) * LDA + (idx & 15) * 8] = *(const float4*)&Btt[idx * 8];
    }

    f32x4 acc[2][8];
#pragma unroll
    for (int mt = 0; mt < 2; ++mt)
#pragma unroll
        for (int nt = 0; nt < 8; ++nt) acc[mt][nt] = (f32x4){0.f, 0.f, 0.f, 0.f};

    __syncthreads();
    // MFMA half 0: nt = 0..3
#pragma unroll
    for (int ks = 0; ks < 4; ++ks) {
        const int k0 = ks * 32 + lk;
        short8 af0 = *(const short8*)&As[(wave * 32 + lm) * LDA + k0];
        short8 af1 = *(const short8*)&As[(wave * 32 + 16 + lm) * LDA + k0];
#pragma unroll
        for (int nt = 0; nt < 4; ++nt) {
            short8 bf = *(const short8*)&Bs[(nt * 16 + lm) * LDA + k0];
            acc[0][nt] = __builtin_amdgcn_mfma_f32_16x16x32_bf16(af0, bf, acc[0][nt], 0, 0, 0);
            acc[1][nt] = __builtin_amdgcn_mfma_f32_16x16x32_bf16(af1, bf, acc[1][nt], 0, 0, 0);
        }
    }
    __syncthreads();
    // stage B half 1 (rows 64..127)
#pragma unroll
    for (int i = 0; i < 4; ++i) {
        int idx = i * 256 + tid;
        *(float4*)&Bs[(idx >> 4) * LDA + (idx & 15) * 8] = *(const float4*)&Btt[(1024 + idx) * 8];
    }
    __syncthreads();
    // MFMA half 1: nt = 4..7
#pragma unroll
    for (int ks = 0; ks < 4; ++ks) {
        const int k0 = ks * 32 + lk;
        short8 af0 = *(const short8*)&As[(wave * 32 + lm) * LDA + k0];
        short8 af1 = *(const short8*)&As[(wave * 32 + 16 + lm) * LDA + k0];
#pragma unroll
        for (int nt = 4; nt < 8; ++nt) {
            short8 bf = *(const short8*)&Bs[((nt - 4) * 16 + lm) * LDA + k0];
            acc[0][nt] = __builtin_amdgcn_mfma_f32_16x16x32_bf16(af0, bf, acc[0][nt], 0, 0, 0);
            acc[1][nt] = __builtin_amdgcn_mfma_f32_16x16x32_bf16(af1, bf, acc[1][nt], 0, 0, 0);
        }
    }

    // packed epilogue with dead-block skip: rel block ct is read only if outmask[row] bit (ct-1) set.
    // (C/D layout: logical col = nt*16+lm, row = wave*32 + mt*16 + (lane>>4)*4 + reg)
    const int rquad = (lane >> 4) * 4;
#pragma unroll
    for (int mt = 0; mt < 2; ++mt)
#pragma unroll
        for (int reg = 0; reg < 4; ++reg) {
            int row = rowBase + wave * 32 + mt * 16 + rquad + reg;
            if (row >= M) continue;
            if (ctile > 0 && !((outmask[row] >> (ctile - 1)) & 1)) continue;  // dead rel-block
            u32x4 qv;
#pragma unroll
            for (int j = 0; j < 4; ++j) {
                unsigned lo = f2bf(acc[mt][2 * j][reg]);
                unsigned hi = f2bf(acc[mt][2 * j + 1][reg]);
                qv[j] = lo | (hi << 16);
            }
            *(u32x4*)((char*)z + (size_t)row * (ZW * 2) + ctile * 256 + lm * 16) = qv;
        }
}

// ---------- gather: 2 edges per load instruction (lane halves), ballot-based means ----------
// lanes 0-31 handle even edges, 32-63 odd; lane q reads uint2 = phys cols 4q..4q+3 of the row.
// halves combined via shfl_xor(.,32) at the end.
__global__ __launch_bounds__(256) void gather_out(const unsigned short* __restrict__ z,
                                                  const int* __restrict__ deg,
                                                  const unsigned int* __restrict__ epk,
                                                  const unsigned long long* __restrict__ ovf,
                                                  const int* __restrict__ ovfc,
                                                  const float* __restrict__ bias,
                                                  const float* __restrict__ Wc,
                                                  const float* __restrict__ bc,
                                                  unsigned short* __restrict__ outb,
                                                  float* __restrict__ outf,
                                                  int N, int mode) {
    const int lane = threadIdx.x & 63;
    const int node = (int)((blockIdx.x * 256 + threadIdx.x) >> 6);
    if (node >= N) return;
    const unsigned int* z32 = (const unsigned int*)z;   // 2 bf16 per uint
    const int half = lane >> 5;      // 0: even edges, 1: odd edges
    const int q = lane & 31;         // column-pair index (phys uints 2q, 2q+1)

    // independent loads: own root row (uint2), degree, padded edge slots
    uint2 vr = *(const uint2*)(z32 + (size_t)node * ZW2 + 2 * q);
    int dt = __builtin_amdgcn_readfirstlane(deg[node]);
    unsigned int ep_v = epk[(size_t)node * MAXDEG + lane];
    const int degc = (dt < MAXDEG) ? dt : MAXDEG;
    const int rel_l = (int)(ep_v & 7u);
    const bool valid = lane < degc;

    // per-rel counts (lane r holds cnt_r)
    int cnt_l = 0;
#pragma unroll
    for (int r = 0; r < 8; ++r) {
        unsigned long long m = __ballot(valid && (rel_l == r));
        int c = (int)__popcll(m);
        if (lane == r) cnt_l = c;
    }
    if (dt > MAXDEG) {   // rare overflow: include spilled edges in counts
        int oc = __builtin_amdgcn_readfirstlane(ovfc[0]);
        for (int j = 0; j < oc; ++j) {
            unsigned long long v = ovf[j];
            if ((int)(v >> 32) == node && lane == (int)(v & 7u)) cnt_l++;
        }
    }
    float winv = 1.0f / (float)((cnt_l < 1) ? 1 : cnt_l);   // lanes>=8 unused

    float t0 = 0.f, t1 = 0.f, t2 = 0.f, t3 = 0.f;
#pragma unroll 1
    for (int g = 0; g < degc; g += 16) {      // 16 edges per group (8 per half)
        uint2 vb[8];
        float wb[8];
#pragma unroll
        for (int k = 0; k < 8; ++k) {
            int i = g + 2 * k + half;                       // this lane's edge index
            int ic = (i < degc) ? i : (degc - 1);           // clamp: loads stay unconditional
            unsigned pk = (unsigned)__shfl((int)ep_v, ic);
            int rel = (int)(pk & 7u);
            unsigned base = (pk >> 3) * ZW2 + (unsigned)(rel + 1) * 64;
            vb[k] = *(const uint2*)(z32 + (size_t)base + 2 * q);
            wb[k] = (i < degc) ? __shfl(winv, rel) : 0.f;   // mask via weight (vb finite)
        }
#pragma unroll
        for (int k = 0; k < 8; ++k) {
            t0 += wb[k] * __uint_as_float(vb[k].x << 16);
            t1 += wb[k] * __uint_as_float(vb[k].x & 0xffff0000u);
            t2 += wb[k] * __uint_as_float(vb[k].y << 16);
            t3 += wb[k] * __uint_as_float(vb[k].y & 0xffff0000u);
        }
    }
    if (dt > MAXDEG) {   // rare overflow: consume spilled edges (half 0 only)
        int oc = __builtin_amdgcn_readfirstlane(ovfc[0]);
        for (int j = 0; j < oc; ++j) {
            unsigned long long v = ovf[j];
            if ((int)(v >> 32) == node) {
                unsigned pk = (unsigned)(v & 0xffffffffu);
                int rel = (int)(pk & 7u);
                unsigned base = (pk >> 3) * ZW2 + (unsigned)(rel + 1) * 64;
                uint2 u = *(const uint2*)(z32 + (size_t)base + 2 * q);
                float w = __shfl(winv, rel);
                if (half == 0) {
                    t0 += w * __uint_as_float(u.x << 16);
                    t1 += w * __uint_as_float(u.x & 0xffff0000u);
                    t2 += w * __uint_as_float(u.y << 16);
                    t3 += w * __uint_as_float(u.y & 0xffff0000u);
                }
            }
        }
    }

    // combine the two edge-halves: lane q and lane q+32 hold the same 4 columns
    t0 += __shfl_xor(t0, 32);
    t1 += __shfl_xor(t1, 32);
    t2 += __shfl_xor(t2, 32);
    t3 += __shfl_xor(t3, 32);

    // logical columns for phys cols p0..p0+3:  c = ((p&7)<<4) + (p>>3)
    const int p0 = 4 * q;
    const int c0 = ((p0 & 7) << 4) + (p0 >> 3);
    const int c1 = (((p0 + 1) & 7) << 4) + ((p0 + 1) >> 3);
    const int c2 = (((p0 + 2) & 7) << 4) + ((p0 + 2) >> 3);
    const int c3 = (((p0 + 3) & 7) << 4) + ((p0 + 3) >> 3);

    // root + bias + relu
    t0 = fmaxf(t0 + __uint_as_float(vr.x << 16)         + bias[c0], 0.f);
    t1 = fmaxf(t1 + __uint_as_float(vr.x & 0xffff0000u) + bias[c1], 0.f);
    t2 = fmaxf(t2 + __uint_as_float(vr.y << 16)         + bias[c2], 0.f);
    t3 = fmaxf(t3 + __uint_as_float(vr.y & 0xffff0000u) + bias[c3], 0.f);

    if (mode == 1) {
        if (half == 0) {       // lanes 0-31 write the 256-B row (phys layout preserved)
            uint2 o;
            o.x = (unsigned)f2bf(t0) | ((unsigned)f2bf(t1) << 16);
            o.y = (unsigned)f2bf(t2) | ((unsigned)f2bf(t3) << 16);
            *(uint2*)((unsigned int*)outb + (size_t)node * 64 + 2 * q) = o;
        }
    } else {
        float s = t0 * Wc[c0] + t1 * Wc[c1] + t2 * Wc[c2] + t3 * Wc[c3];
        s += __shfl_xor(s, 1);
        s += __shfl_xor(s, 2);
        s += __shfl_xor(s, 4);
        s += __shfl_xor(s, 8);
        s += __shfl_xor(s, 16);
        if (lane == 0) outf[node] = s + bc[0];
    }
}

extern "C" void kernel_launch(void* const* d_in, const int* in_sizes, int n_in,
                              void* d_out, int out_size, void* d_ws, size_t ws_size,
                              hipStream_t stream) {
    const float* x     = (const float*)d_in[0];
    const int*   ei    = (const int*)d_in[1];
    const int*   et    = (const int*)d_in[2];
    const float* W1    = (const float*)d_in[3];
    const float* root1 = (const float*)d_in[4];
    const float* b1    = (const float*)d_in[5];
    const float* W2    = (const float*)d_in[6];
    const float* root2 = (const float*)d_in[7];
    const float* b2    = (const float*)d_in[8];
    const float* Wc    = (const float*)d_in[9];
    const float* bc    = (const float*)d_in[10];
    float* out = (float*)d_out;

    const int N = in_sizes[0] / Hd;
    const int E = in_sizes[2];
    const int* src  = ei;
    const int* dstp = ei + E;

    const size_t NH = (size_t)N * Hd;

    size_t off = 0;
    auto carve = [&](size_t bytes) -> char* {
        char* p = (char*)d_ws + off;
        off += (bytes + 255) & ~(size_t)255;
        return p;
    };
    unsigned short* hbf   = (unsigned short*)carve(NH * 2);           // h (layer-1 out, layer-2 A)
    unsigned short* z     = (unsigned short*)carve((size_t)N * ZW * 2);
    unsigned short* Bt    = (unsigned short*)carve((size_t)2 * 9 * 16384 * 2);
    int*            deg   = (int*)carve((size_t)N * 4);
    int*            ovfc  = (int*)carve(4);
    int*            outm  = (int*)carve((size_t)N * 4);
    unsigned long long* ovf = (unsigned long long*)carve((size_t)E * 8);
    unsigned int*   epk   = (unsigned int*)carve((size_t)N * MAXDEG * 4);
    if (off > ws_size) return;

    // zero deg + ovfc + outmask in one memset (contiguous carves)
    size_t zspan = (size_t)((char*)ovf - (char*)deg);
    hipMemsetAsync(deg, 0, zspan, stream);

    // merged prep: weight transpose + edge placement (+outmask)
    const int eBlocks = (E + 255) / 256;
    prep_kernel<<<18 + eBlocks, 256, 0, stream>>>(root1, W1, root2, W2, Bt,
                                                  src, dstp, et, E, deg, outm, epk, ovf, ovfc);

    const int Mtiles = (N + 127) / 128;
    const int nodeBlocks = (N + 3) / 4;

    // layer 1: z = x @ [root1|W1...] (inline fp32->bf16 A cvt), aggregate -> h (relu, bf16)
    gemm_z<<<Mtiles * 9, 256, 0, stream>>>(nullptr, x, Bt, outm, z, N);
    gather_out<<<nodeBlocks, 256, 0, stream>>>(z, deg, epk, ovf, ovfc, b1, nullptr, nullptr,
                                               hbf, nullptr, N, 1);
    // layer 2: z = h @ [root2|W2...] (K-permuted weights), aggregate + classifier -> out
    gemm_z<<<Mtiles * 9, 256, 0, stream>>>(hbf, nullptr, Bt + (size_t)9 * 16384, outm, z, N);
    gather_out<<<nodeBlocks, 256, 0, stream>>>(z, deg, epk, ovf, ovfc, b2, Wc, bc,
                                               nullptr, out, N, 2);
}

// Round 12
// 236.558 us; speedup vs baseline: 1.1177x; 1.1177x over previous
//
#include <hip/hip_runtime.h>

#define Hd 128
#define LDA 136     // LDS leading dim (bf16 elems)
#define ZW 1152     // z row width (bf16): [root | 8 rels] * 128
#define ZW2 576     // z row width in uints
#define MAXDEG 64   // padded edge slots per dst node

typedef __attribute__((ext_vector_type(8))) short short8;   // 8 bf16 = 4 VGPRs
typedef __attribute__((ext_vector_type(4))) float f32x4;
typedef __attribute__((ext_vector_type(4))) unsigned int u32x4;

__device__ __forceinline__ unsigned short f2bf(float f) {
    union { float f; unsigned u; } v; v.f = f;
    unsigned r = v.u + 0x7FFFu + ((v.u >> 16) & 1u);   // RNE
    return (unsigned short)(r >> 16);
}

// ---------- prep: [0,18) weight transpose (+K-perm for layer-2), [18,530) x cvt ----------
__global__ __launch_bounds__(256) void prep_kernel(const float* __restrict__ x,
                                                   unsigned short* __restrict__ xbf, int n4,
                                                   const float* __restrict__ root1,
                                                   const float* __restrict__ W1,
                                                   const float* __restrict__ root2,
                                                   const float* __restrict__ W2,
                                                   unsigned short* __restrict__ Bt) {
    const int tid = threadIdx.x;
    if (blockIdx.x < 18) {
        // Bt[b][n*128 + kp] = bf16(W[k][n]); kp = perm(k) for b>=9 (layer-2 K matches permuted h)
        __shared__ float S[32 * 129];
        const int b = blockIdx.x;
        const float* Ws;
        if (b == 0)       Ws = root1;
        else if (b < 9)   Ws = W1 + (size_t)(b - 1) * 16384;
        else if (b == 9)  Ws = root2;
        else              Ws = W2 + (size_t)(b - 10) * 16384;
        unsigned short* Bd = Bt + (size_t)b * 16384;
        for (int s = 0; s < 4; ++s) {
            __syncthreads();
#pragma unroll
            for (int i = 0; i < 16; ++i) {     // load rows k in [32s,32s+32)
                int idx = i * 256 + tid;
                int k = idx >> 7, n = idx & 127;
                S[k * 129 + n] = Ws[(size_t)(32 * s + k) * 128 + n];
            }
            __syncthreads();
#pragma unroll
            for (int i = 0; i < 16; ++i) {     // write Bd[n][kp]
                int idx = i * 256 + tid;
                int n = idx >> 5, kk = idx & 31;
                int k = 32 * s + kk;
                int kp = (b >= 9) ? (((k & 15) << 3) | (k >> 4)) : k;
                Bd[n * 128 + kp] = f2bf(S[kk * 129 + n]);
            }
        }
    } else {
        // grid-stride fp32 -> bf16 of x
        const int stride = 512 * 256;
        for (int i = (blockIdx.x - 18) * 256 + tid; i < n4; i += stride) {
            float4 v = ((const float4*)x)[i];
            ushort4 o;
            o.x = f2bf(v.x); o.y = f2bf(v.y); o.z = f2bf(v.z); o.w = f2bf(v.w);
            ((ushort4*)xbf)[i] = o;
        }
    }
}

// ---------- dense GEMM (+ co-scheduled edge placement): split-B (3 blocks/CU), XCD swizzle ----------
// blocks [0, nEdge): edge placement (latency-bound; overlaps GEMM compute).
// blocks [nEdge, ..): z[:, ct-block] = A @ Bt[ct].  z phys col order: p=(c&15)*8+(c>>4)
__global__ __launch_bounds__(256, 3) void gemm_z(const unsigned short* __restrict__ A,
                                                 const unsigned short* __restrict__ Bt9,
                                                 unsigned short* __restrict__ z, int M,
                                                 int nEdge,
                                                 const int* __restrict__ src,
                                                 const int* __restrict__ dstp,
                                                 const int* __restrict__ et, int E,
                                                 int* __restrict__ deg,
                                                 unsigned int* __restrict__ epk,
                                                 unsigned long long* __restrict__ ovf,
                                                 int* __restrict__ ovfc) {
    __shared__ __align__(16) unsigned short As[128 * LDA];   // 34816 B
    __shared__ __align__(16) unsigned short Bs[64 * LDA];    // 17408 B
    const int tid = threadIdx.x;

    if ((int)blockIdx.x < nEdge) {
        // edge placement: epk[dst*64 + idx] = src*8 + rel; overflow -> spill list
        int e = blockIdx.x * 256 + tid;
        if (e < E) {
            int r = et[e];
            int d = dstp[e];
            int idx = atomicAdd(&deg[d], 1);
            unsigned pay = ((unsigned)src[e] << 3) | (unsigned)r;
            if (idx < MAXDEG) epk[(size_t)d * MAXDEG + idx] = pay;
            else {
                int o = atomicAdd(ovfc, 1);
                ovf[o] = ((unsigned long long)(unsigned)d << 32) | pay;
            }
        }
        return;
    }

    // bijective XCD swizzle over the GEMM sub-grid: same-mtile blocks on one XCD -> A L2 reuse
    const int bid = (int)blockIdx.x - nEdge;
    const int nwg = (int)gridDim.x - nEdge;
    const int nq = nwg >> 3, rr = nwg & 7;
    const int xcd = bid & 7, bix = bid >> 3;
    const int swz = (xcd < rr ? xcd * (nq + 1) : rr * (nq + 1) + (xcd - rr) * nq) + bix;
    const int mtile = swz / 9, ctile = swz % 9;

    const int rowBase = mtile * 128;
    const int wave = tid >> 6, lane = tid & 63;
    const int lm = lane & 15, lk = (lane >> 4) * 8;
    const unsigned short* Btt = Bt9 + (size_t)ctile * 16384;

    // stage A-tile (full) + B half 0 (rows 0..63)
#pragma unroll
    for (int i = 0; i < 8; ++i) {
        int idx = i * 256 + tid;
        int r = idx >> 4, c16 = idx & 15;
        int grow = rowBase + r; if (grow >= M) grow = M - 1;
        *(float4*)&As[r * LDA + c16 * 8] = *(const float4*)&A[(size_t)grow * Hd + c16 * 8];
    }
#pragma unroll
    for (int i = 0; i < 4; ++i) {
        int idx = i * 256 + tid;             // 0..1023 = 64 rows x 16 float4
        *(float4*)&Bs[(idx >> 4) * LDA + (idx & 15) * 8] = *(const float4*)&Btt[idx * 8];
    }

    f32x4 acc[2][8];
#pragma unroll
    for (int mt = 0; mt < 2; ++mt)
#pragma unroll
        for (int nt = 0; nt < 8; ++nt) acc[mt][nt] = (f32x4){0.f, 0.f, 0.f, 0.f};

    __syncthreads();
    // MFMA half 0: nt = 0..3
#pragma unroll
    for (int ks = 0; ks < 4; ++ks) {
        const int k0 = ks * 32 + lk;
        short8 af0 = *(const short8*)&As[(wave * 32 + lm) * LDA + k0];
        short8 af1 = *(const short8*)&As[(wave * 32 + 16 + lm) * LDA + k0];
#pragma unroll
        for (int nt = 0; nt < 4; ++nt) {
            short8 bf = *(const short8*)&Bs[(nt * 16 + lm) * LDA + k0];
            acc[0][nt] = __builtin_amdgcn_mfma_f32_16x16x32_bf16(af0, bf, acc[0][nt], 0, 0, 0);
            acc[1][nt] = __builtin_amdgcn_mfma_f32_16x16x32_bf16(af1, bf, acc[1][nt], 0, 0, 0);
        }
    }
    __syncthreads();
    // stage B half 1 (rows 64..127)
#pragma unroll
    for (int i = 0; i < 4; ++i) {
        int idx = i * 256 + tid;
        *(float4*)&Bs[(idx >> 4) * LDA + (idx & 15) * 8] = *(const float4*)&Btt[(1024 + idx) * 8];
    }
    __syncthreads();
    // MFMA half 1: nt = 4..7
#pragma unroll
    for (int ks = 0; ks < 4; ++ks) {
        const int k0 = ks * 32 + lk;
        short8 af0 = *(const short8*)&As[(wave * 32 + lm) * LDA + k0];
        short8 af1 = *(const short8*)&As[(wave * 32 + 16 + lm) * LDA + k0];
#pragma unroll
        for (int nt = 4; nt < 8; ++nt) {
            short8 bf = *(const short8*)&Bs[((nt - 4) * 16 + lm) * LDA + k0];
            acc[0][nt] = __builtin_amdgcn_mfma_f32_16x16x32_bf16(af0, bf, acc[0][nt], 0, 0, 0);
            acc[1][nt] = __builtin_amdgcn_mfma_f32_16x16x32_bf16(af1, bf, acc[1][nt], 0, 0, 0);
        }
    }

    // packed epilogue: lane lm owns phys cols lm*8..lm*8+7 -> one dwordx4 per (mt,reg)
    // (C/D layout: logical col = nt*16+lm, row = wave*32 + mt*16 + (lane>>4)*4 + reg)
    const int rquad = (lane >> 4) * 4;
#pragma unroll
    for (int mt = 0; mt < 2; ++mt)
#pragma unroll
        for (int reg = 0; reg < 4; ++reg) {
            int row = rowBase + wave * 32 + mt * 16 + rquad + reg;
            if (row >= M) continue;
            u32x4 qv;
#pragma unroll
            for (int j = 0; j < 4; ++j) {
                unsigned lo = f2bf(acc[mt][2 * j][reg]);
                unsigned hi = f2bf(acc[mt][2 * j + 1][reg]);
                qv[j] = lo | (hi << 16);
            }
            *(u32x4*)((char*)z + (size_t)row * (ZW * 2) + ctile * 256 + lm * 16) = qv;
        }
}

// ---------- gather: 2 edges per load instruction (lane halves), ballot-based means ----------
// lanes 0-31 handle even edges, 32-63 odd; lane q reads uint2 = phys cols 4q..4q+3 of the row.
// halves combined via shfl_xor(.,32) at the end.
__global__ __launch_bounds__(256) void gather_out(const unsigned short* __restrict__ z,
                                                  const int* __restrict__ deg,
                                                  const unsigned int* __restrict__ epk,
                                                  const unsigned long long* __restrict__ ovf,
                                                  const int* __restrict__ ovfc,
                                                  const float* __restrict__ bias,
                                                  const float* __restrict__ Wc,
                                                  const float* __restrict__ bc,
                                                  unsigned short* __restrict__ outb,
                                                  float* __restrict__ outf,
                                                  int N, int mode) {
    const int lane = threadIdx.x & 63;
    const int node = (int)((blockIdx.x * 256 + threadIdx.x) >> 6);
    if (node >= N) return;
    const unsigned int* z32 = (const unsigned int*)z;   // 2 bf16 per uint
    const int half = lane >> 5;      // 0: even edges, 1: odd edges
    const int q = lane & 31;         // column-pair index (phys uints 2q, 2q+1)

    // independent loads: own root row (uint2), degree, padded edge slots
    uint2 vr = *(const uint2*)(z32 + (size_t)node * ZW2 + 2 * q);
    int dt = __builtin_amdgcn_readfirstlane(deg[node]);
    unsigned int ep_v = epk[(size_t)node * MAXDEG + lane];
    const int degc = (dt < MAXDEG) ? dt : MAXDEG;
    const int rel_l = (int)(ep_v & 7u);
    const bool valid = lane < degc;

    // per-rel counts (lane r holds cnt_r)
    int cnt_l = 0;
#pragma unroll
    for (int r = 0; r < 8; ++r) {
        unsigned long long m = __ballot(valid && (rel_l == r));
        int c = (int)__popcll(m);
        if (lane == r) cnt_l = c;
    }
    if (dt > MAXDEG) {   // rare overflow: include spilled edges in counts
        int oc = __builtin_amdgcn_readfirstlane(ovfc[0]);
        for (int j = 0; j < oc; ++j) {
            unsigned long long v = ovf[j];
            if ((int)(v >> 32) == node && lane == (int)(v & 7u)) cnt_l++;
        }
    }
    float winv = 1.0f / (float)((cnt_l < 1) ? 1 : cnt_l);   // lanes>=8 unused

    float t0 = 0.f, t1 = 0.f, t2 = 0.f, t3 = 0.f;
#pragma unroll 1
    for (int g = 0; g < degc; g += 16) {      // 16 edges per group (8 per half)
        uint2 vb[8];
        float wb[8];
#pragma unroll
        for (int k = 0; k < 8; ++k) {
            int i = g + 2 * k + half;                       // this lane's edge index
            int ic = (i < degc) ? i : (degc - 1);           // clamp: loads stay unconditional
            unsigned pk = (unsigned)__shfl((int)ep_v, ic);
            int rel = (int)(pk & 7u);
            unsigned base = (pk >> 3) * ZW2 + (unsigned)(rel + 1) * 64;
            vb[k] = *(const uint2*)(z32 + (size_t)base + 2 * q);
            wb[k] = (i < degc) ? __shfl(winv, rel) : 0.f;   // mask via weight (vb finite)
        }
#pragma unroll
        for (int k = 0; k < 8; ++k) {
            t0 += wb[k] * __uint_as_float(vb[k].x << 16);
            t1 += wb[k] * __uint_as_float(vb[k].x & 0xffff0000u);
            t2 += wb[k] * __uint_as_float(vb[k].y << 16);
            t3 += wb[k] * __uint_as_float(vb[k].y & 0xffff0000u);
        }
    }
    if (dt > MAXDEG) {   // rare overflow: consume spilled edges (half 0 only)
        int oc = __builtin_amdgcn_readfirstlane(ovfc[0]);
        for (int j = 0; j < oc; ++j) {
            unsigned long long v = ovf[j];
            if ((int)(v >> 32) == node) {
                unsigned pk = (unsigned)(v & 0xffffffffu);
                int rel = (int)(pk & 7u);
                unsigned base = (pk >> 3) * ZW2 + (unsigned)(rel + 1) * 64;
                uint2 u = *(const uint2*)(z32 + (size_t)base + 2 * q);
                float w = __shfl(winv, rel);
                if (half == 0) {
                    t0 += w * __uint_as_float(u.x << 16);
                    t1 += w * __uint_as_float(u.x & 0xffff0000u);
                    t2 += w * __uint_as_float(u.y << 16);
                    t3 += w * __uint_as_float(u.y & 0xffff0000u);
                }
            }
        }
    }

    // combine the two edge-halves: lane q and lane q+32 hold the same 4 columns
    t0 += __shfl_xor(t0, 32);
    t1 += __shfl_xor(t1, 32);
    t2 += __shfl_xor(t2, 32);
    t3 += __shfl_xor(t3, 32);

    // logical columns for phys cols p0..p0+3:  c = ((p&7)<<4) + (p>>3)
    const int p0 = 4 * q;
    const int c0 = ((p0 & 7) << 4) + (p0 >> 3);
    const int c1 = (((p0 + 1) & 7) << 4) + ((p0 + 1) >> 3);
    const int c2 = (((p0 + 2) & 7) << 4) + ((p0 + 2) >> 3);
    const int c3 = (((p0 + 3) & 7) << 4) + ((p0 + 3) >> 3);

    // root + bias + relu
    t0 = fmaxf(t0 + __uint_as_float(vr.x << 16)         + bias[c0], 0.f);
    t1 = fmaxf(t1 + __uint_as_float(vr.x & 0xffff0000u) + bias[c1], 0.f);
    t2 = fmaxf(t2 + __uint_as_float(vr.y << 16)         + bias[c2], 0.f);
    t3 = fmaxf(t3 + __uint_as_float(vr.y & 0xffff0000u) + bias[c3], 0.f);

    if (mode == 1) {
        if (half == 0) {       // lanes 0-31 write the 256-B row (phys layout preserved)
            uint2 o;
            o.x = (unsigned)f2bf(t0) | ((unsigned)f2bf(t1) << 16);
            o.y = (unsigned)f2bf(t2) | ((unsigned)f2bf(t3) << 16);
            *(uint2*)((unsigned int*)outb + (size_t)node * 64 + 2 * q) = o;
        }
    } else {
        float s = t0 * Wc[c0] + t1 * Wc[c1] + t2 * Wc[c2] + t3 * Wc[c3];
        s += __shfl_xor(s, 1);
        s += __shfl_xor(s, 2);
        s += __shfl_xor(s, 4);
        s += __shfl_xor(s, 8);
        s += __shfl_xor(s, 16);
        if (lane == 0) outf[node] = s + bc[0];
    }
}

extern "C" void kernel_launch(void* const* d_in, const int* in_sizes, int n_in,
                              void* d_out, int out_size, void* d_ws, size_t ws_size,
                              hipStream_t stream) {
    const float* x     = (const float*)d_in[0];
    const int*   ei    = (const int*)d_in[1];
    const int*   et    = (const int*)d_in[2];
    const float* W1    = (const float*)d_in[3];
    const float* root1 = (const float*)d_in[4];
    const float* b1    = (const float*)d_in[5];
    const float* W2    = (const float*)d_in[6];
    const float* root2 = (const float*)d_in[7];
    const float* b2    = (const float*)d_in[8];
    const float* Wc    = (const float*)d_in[9];
    const float* bc    = (const float*)d_in[10];
    float* out = (float*)d_out;

    const int N = in_sizes[0] / Hd;
    const int E = in_sizes[2];
    const int* src  = ei;
    const int* dstp = ei + E;

    const size_t NH = (size_t)N * Hd;

    size_t off = 0;
    auto carve = [&](size_t bytes) -> char* {
        char* p = (char*)d_ws + off;
        off += (bytes + 255) & ~(size_t)255;
        return p;
    };
    unsigned short* xbf  = (unsigned short*)carve(NH * 2);            // also h (layer-2 A) after gather-1
    unsigned short* z    = (unsigned short*)carve((size_t)N * ZW * 2);
    unsigned short* Bt   = (unsigned short*)carve((size_t)2 * 9 * 16384 * 2);
    int*            deg  = (int*)carve((size_t)N * 4);
    int*            ovfc = (int*)carve(4);
    unsigned long long* ovf = (unsigned long long*)carve((size_t)E * 8);
    unsigned int*   epk  = (unsigned int*)carve((size_t)N * MAXDEG * 4);
    if (off > ws_size) return;

    // zero deg + ovfc in one memset (contiguous carves)
    size_t zspan = (size_t)((char*)ovfc - (char*)deg) + 256;
    hipMemsetAsync(deg, 0, zspan, stream);

    // prep: weight transpose + x cvt (edge placement moved into gemm-1's grid)
    const int n4 = (int)(NH / 4);
    prep_kernel<<<530, 256, 0, stream>>>(x, xbf, n4, root1, W1, root2, W2, Bt);

    const int Mtiles = (N + 127) / 128;
    const int nodeBlocks = (N + 3) / 4;
    const int eBlocks = (E + 255) / 256;

    // layer 1: [edge placement || z = x @ [root1|W1...]], then aggregate -> h (relu, bf16)
    gemm_z<<<eBlocks + Mtiles * 9, 256, 0, stream>>>(xbf, Bt, z, N, eBlocks,
                                                     src, dstp, et, E, deg, epk, ovf, ovfc);
    gather_out<<<nodeBlocks, 256, 0, stream>>>(z, deg, epk, ovf, ovfc, b1, nullptr, nullptr,
                                               xbf, nullptr, N, 1);
    // layer 2: z = h @ [root2|W2...] (K-permuted weights), aggregate + classifier -> out
    gemm_z<<<Mtiles * 9, 256, 0, stream>>>(xbf, Bt + (size_t)9 * 16384, z, N, 0,
                                           nullptr, nullptr, nullptr, 0,
                                           nullptr, nullptr, nullptr, nullptr);
    gather_out<<<nodeBlocks, 256, 0, stream>>>(z, deg, epk, ovf, ovfc, b2, Wc, bc,
                                               nullptr, out, N, 2);
}

// Round 13
// 226.271 us; speedup vs baseline: 1.1685x; 1.0455x over previous
//
#include <hip/hip_runtime.h>

#define Hd 128
#define LDA 136     // LDS leading dim (bf16 elems)
#define ZW 1152     // z row width (bf16): [root | 8 rels] * 128
#define ZW2 576     // z row width in uints
#define MAXDEG 64   // padded edge slots per dst node

typedef __attribute__((ext_vector_type(8))) short short8;   // 8 bf16 = 4 VGPRs
typedef __attribute__((ext_vector_type(4))) float f32x4;
typedef __attribute__((ext_vector_type(4))) unsigned int u32x4;

__device__ __forceinline__ unsigned short f2bf(float f) {
    union { float f; unsigned u; } v; v.f = f;
    unsigned r = v.u + 0x7FFFu + ((v.u >> 16) & 1u);   // RNE
    return (unsigned short)(r >> 16);
}

// ---------- merged prep: [0,18) weight transpose (+K-perm for layer-2), [18,530) x cvt,
// [530,..) edge placement into padded slots (no CSR, no scan) ----------
__global__ __launch_bounds__(256) void prep_kernel(const float* __restrict__ x,
                                                   unsigned short* __restrict__ xbf, int n4,
                                                   const float* __restrict__ root1,
                                                   const float* __restrict__ W1,
                                                   const float* __restrict__ root2,
                                                   const float* __restrict__ W2,
                                                   unsigned short* __restrict__ Bt,
                                                   const int* __restrict__ src,
                                                   const int* __restrict__ dstp,
                                                   const int* __restrict__ et, int E,
                                                   int* __restrict__ deg,
                                                   unsigned int* __restrict__ epk,
                                                   unsigned long long* __restrict__ ovf,
                                                   int* __restrict__ ovfc) {
    const int tid = threadIdx.x;
    if (blockIdx.x < 18) {
        // Bt[b][n*128 + kp] = bf16(W[k][n]); kp = perm(k) for b>=9 (layer-2 K matches permuted h)
        __shared__ float S[32 * 129];
        const int b = blockIdx.x;
        const float* Ws;
        if (b == 0)       Ws = root1;
        else if (b < 9)   Ws = W1 + (size_t)(b - 1) * 16384;
        else if (b == 9)  Ws = root2;
        else              Ws = W2 + (size_t)(b - 10) * 16384;
        unsigned short* Bd = Bt + (size_t)b * 16384;
        for (int s = 0; s < 4; ++s) {
            __syncthreads();
#pragma unroll
            for (int i = 0; i < 16; ++i) {     // load rows k in [32s,32s+32)
                int idx = i * 256 + tid;
                int k = idx >> 7, n = idx & 127;
                S[k * 129 + n] = Ws[(size_t)(32 * s + k) * 128 + n];
            }
            __syncthreads();
#pragma unroll
            for (int i = 0; i < 16; ++i) {     // write Bd[n][kp]
                int idx = i * 256 + tid;
                int n = idx >> 5, kk = idx & 31;
                int k = 32 * s + kk;
                int kp = (b >= 9) ? (((k & 15) << 3) | (k >> 4)) : k;
                Bd[n * 128 + kp] = f2bf(S[kk * 129 + n]);
            }
        }
    } else if (blockIdx.x < 18 + 512) {
        // grid-stride fp32 -> bf16 of x
        const int stride = 512 * 256;
        for (int i = (blockIdx.x - 18) * 256 + tid; i < n4; i += stride) {
            float4 v = ((const float4*)x)[i];
            ushort4 o;
            o.x = f2bf(v.x); o.y = f2bf(v.y); o.z = f2bf(v.z); o.w = f2bf(v.w);
            ((ushort4*)xbf)[i] = o;
        }
    } else {
        // edge placement: epk[dst*64 + idx] = src*8 + rel; overflow -> spill list
        int e = (blockIdx.x - 530) * 256 + tid;
        if (e < E) {
            int r = et[e];
            int d = dstp[e];
            int idx = atomicAdd(&deg[d], 1);
            unsigned pay = ((unsigned)src[e] << 3) | (unsigned)r;
            if (idx < MAXDEG) epk[(size_t)d * MAXDEG + idx] = pay;
            else {
                int o = atomicAdd(ovfc, 1);
                ovf[o] = ((unsigned long long)(unsigned)d << 32) | pay;
            }
        }
    }
}

// ---------- dense GEMM: z[:, ct-block] = A @ Bt[ct]; split-B staging -> 3 blocks/CU ----------
// LDS: As 128x128 (34.8KB) + Bs 64x128 half-tile (17.4KB) = 52.2KB  =>  3 blocks/CU.
// z physical column order within each 128-block: p = (c&15)*8 + (c>>4)
__global__ __launch_bounds__(256, 3) void gemm_z(const unsigned short* __restrict__ A,
                                                 const unsigned short* __restrict__ Bt9,
                                                 unsigned short* __restrict__ z, int M) {
    __shared__ __align__(16) unsigned short As[128 * LDA];   // 34816 B
    __shared__ __align__(16) unsigned short Bs[64 * LDA];    // 17408 B
    const int tid = threadIdx.x;

    // bijective XCD swizzle: same-mtile blocks land on one XCD -> A-tile L2 reuse
    const int nwg = gridDim.x;
    const int nq = nwg >> 3, rr = nwg & 7;
    const int xcd = blockIdx.x & 7, bix = blockIdx.x >> 3;
    const int swz = (xcd < rr ? xcd * (nq + 1) : rr * (nq + 1) + (xcd - rr) * nq) + bix;
    const int mtile = swz / 9, ctile = swz % 9;

    const int rowBase = mtile * 128;
    const int wave = tid >> 6, lane = tid & 63;
    const int lm = lane & 15, lk = (lane >> 4) * 8;
    const unsigned short* Btt = Bt9 + (size_t)ctile * 16384;

    // stage A-tile (full) + B half 0 (rows 0..63)
#pragma unroll
    for (int i = 0; i < 8; ++i) {
        int idx = i * 256 + tid;
        int r = idx >> 4, c16 = idx & 15;
        int grow = rowBase + r; if (grow >= M) grow = M - 1;
        *(float4*)&As[r * LDA + c16 * 8] = *(const float4*)&A[(size_t)grow * Hd + c16 * 8];
    }
#pragma unroll
    for (int i = 0; i < 4; ++i) {
        int idx = i * 256 + tid;             // 0..1023 = 64 rows x 16 float4
        *(float4*)&Bs[(idx >> 4) * LDA + (idx & 15) * 8] = *(const float4*)&Btt[idx * 8];
    }

    f32x4 acc[2][8];
#pragma unroll
    for (int mt = 0; mt < 2; ++mt)
#pragma unroll
        for (int nt = 0; nt < 8; ++nt) acc[mt][nt] = (f32x4){0.f, 0.f, 0.f, 0.f};

    __syncthreads();
    // MFMA half 0: nt = 0..3
#pragma unroll
    for (int ks = 0; ks < 4; ++ks) {
        const int k0 = ks * 32 + lk;
        short8 af0 = *(const short8*)&As[(wave * 32 + lm) * LDA + k0];
        short8 af1 = *(const short8*)&As[(wave * 32 + 16 + lm) * LDA + k0];
#pragma unroll
        for (int nt = 0; nt < 4; ++nt) {
            short8 bf = *(const short8*)&Bs[(nt * 16 + lm) * LDA + k0];
            acc[0][nt] = __builtin_amdgcn_mfma_f32_16x16x32_bf16(af0, bf, acc[0][nt], 0, 0, 0);
            acc[1][nt] = __builtin_amdgcn_mfma_f32_16x16x32_bf16(af1, bf, acc[1][nt], 0, 0, 0);
        }
    }
    __syncthreads();
    // stage B half 1 (rows 64..127)
#pragma unroll
    for (int i = 0; i < 4; ++i) {
        int idx = i * 256 + tid;
        *(float4*)&Bs[(idx >> 4) * LDA + (idx & 15) * 8] = *(const float4*)&Btt[(1024 + idx) * 8];
    }
    __syncthreads();
    // MFMA half 1: nt = 4..7
#pragma unroll
    for (int ks = 0; ks < 4; ++ks) {
        const int k0 = ks * 32 + lk;
        short8 af0 = *(const short8*)&As[(wave * 32 + lm) * LDA + k0];
        short8 af1 = *(const short8*)&As[(wave * 32 + 16 + lm) * LDA + k0];
#pragma unroll
        for (int nt = 4; nt < 8; ++nt) {
            short8 bf = *(const short8*)&Bs[((nt - 4) * 16 + lm) * LDA + k0];
            acc[0][nt] = __builtin_amdgcn_mfma_f32_16x16x32_bf16(af0, bf, acc[0][nt], 0, 0, 0);
            acc[1][nt] = __builtin_amdgcn_mfma_f32_16x16x32_bf16(af1, bf, acc[1][nt], 0, 0, 0);
        }
    }

    // packed epilogue: lane lm owns phys cols lm*8..lm*8+7 -> one dwordx4 per (mt,reg)
    // (C/D layout: logical col = nt*16+lm, row = wave*32 + mt*16 + (lane>>4)*4 + reg)
    const int rquad = (lane >> 4) * 4;
#pragma unroll
    for (int mt = 0; mt < 2; ++mt)
#pragma unroll
        for (int reg = 0; reg < 4; ++reg) {
            int row = rowBase + wave * 32 + mt * 16 + rquad + reg;
            if (row >= M) continue;
            u32x4 qv;
#pragma unroll
            for (int j = 0; j < 4; ++j) {
                unsigned lo = f2bf(acc[mt][2 * j][reg]);
                unsigned hi = f2bf(acc[mt][2 * j + 1][reg]);
                qv[j] = lo | (hi << 16);
            }
            *(u32x4*)((char*)z + (size_t)row * (ZW * 2) + ctile * 256 + lm * 16) = qv;
        }
}

// ---------- gather: 2 edges per load instruction (lane halves), ballot-based means ----------
// lanes 0-31 handle even edges, 32-63 odd; lane q reads uint2 = phys cols 4q..4q+3 of the row.
// halves combined via shfl_xor(.,32) at the end.
__global__ __launch_bounds__(256) void gather_out(const unsigned short* __restrict__ z,
                                                  const int* __restrict__ deg,
                                                  const unsigned int* __restrict__ epk,
                                                  const unsigned long long* __restrict__ ovf,
                                                  const int* __restrict__ ovfc,
                                                  const float* __restrict__ bias,
                                                  const float* __restrict__ Wc,
                                                  const float* __restrict__ bc,
                                                  unsigned short* __restrict__ outb,
                                                  float* __restrict__ outf,
                                                  int N, int mode) {
    const int lane = threadIdx.x & 63;
    const int node = (int)((blockIdx.x * 256 + threadIdx.x) >> 6);
    if (node >= N) return;
    const unsigned int* z32 = (const unsigned int*)z;   // 2 bf16 per uint
    const int half = lane >> 5;      // 0: even edges, 1: odd edges
    const int q = lane & 31;         // column-pair index (phys uints 2q, 2q+1)

    // independent loads: own root row (uint2), degree, padded edge slots
    uint2 vr = *(const uint2*)(z32 + (size_t)node * ZW2 + 2 * q);
    int dt = __builtin_amdgcn_readfirstlane(deg[node]);
    unsigned int ep_v = epk[(size_t)node * MAXDEG + lane];
    const int degc = (dt < MAXDEG) ? dt : MAXDEG;
    const int rel_l = (int)(ep_v & 7u);
    const bool valid = lane < degc;

    // per-rel counts (lane r holds cnt_r)
    int cnt_l = 0;
#pragma unroll
    for (int r = 0; r < 8; ++r) {
        unsigned long long m = __ballot(valid && (rel_l == r));
        int c = (int)__popcll(m);
        if (lane == r) cnt_l = c;
    }
    if (dt > MAXDEG) {   // rare overflow: include spilled edges in counts
        int oc = __builtin_amdgcn_readfirstlane(ovfc[0]);
        for (int j = 0; j < oc; ++j) {
            unsigned long long v = ovf[j];
            if ((int)(v >> 32) == node && lane == (int)(v & 7u)) cnt_l++;
        }
    }
    float winv = 1.0f / (float)((cnt_l < 1) ? 1 : cnt_l);   // lanes>=8 unused

    float t0 = 0.f, t1 = 0.f, t2 = 0.f, t3 = 0.f;
#pragma unroll 1
    for (int g = 0; g < degc; g += 16) {      // 16 edges per group (8 per half)
        uint2 vb[8];
        float wb[8];
#pragma unroll
        for (int k = 0; k < 8; ++k) {
            int i = g + 2 * k + half;                       // this lane's edge index
            int ic = (i < degc) ? i : (degc - 1);           // clamp: loads stay unconditional
            unsigned pk = (unsigned)__shfl((int)ep_v, ic);
            int rel = (int)(pk & 7u);
            unsigned base = (pk >> 3) * ZW2 + (unsigned)(rel + 1) * 64;
            vb[k] = *(const uint2*)(z32 + (size_t)base + 2 * q);
            wb[k] = (i < degc) ? __shfl(winv, rel) : 0.f;   // mask via weight (vb finite)
        }
#pragma unroll
        for (int k = 0; k < 8; ++k) {
            t0 += wb[k] * __uint_as_float(vb[k].x << 16);
            t1 += wb[k] * __uint_as_float(vb[k].x & 0xffff0000u);
            t2 += wb[k] * __uint_as_float(vb[k].y << 16);
            t3 += wb[k] * __uint_as_float(vb[k].y & 0xffff0000u);
        }
    }
    if (dt > MAXDEG) {   // rare overflow: consume spilled edges (half 0 only)
        int oc = __builtin_amdgcn_readfirstlane(ovfc[0]);
        for (int j = 0; j < oc; ++j) {
            unsigned long long v = ovf[j];
            if ((int)(v >> 32) == node) {
                unsigned pk = (unsigned)(v & 0xffffffffu);
                int rel = (int)(pk & 7u);
                unsigned base = (pk >> 3) * ZW2 + (unsigned)(rel + 1) * 64;
                uint2 u = *(const uint2*)(z32 + (size_t)base + 2 * q);
                float w = __shfl(winv, rel);
                if (half == 0) {
                    t0 += w * __uint_as_float(u.x << 16);
                    t1 += w * __uint_as_float(u.x & 0xffff0000u);
                    t2 += w * __uint_as_float(u.y << 16);
                    t3 += w * __uint_as_float(u.y & 0xffff0000u);
                }
            }
        }
    }

    // combine the two edge-halves: lane q and lane q+32 hold the same 4 columns
    t0 += __shfl_xor(t0, 32);
    t1 += __shfl_xor(t1, 32);
    t2 += __shfl_xor(t2, 32);
    t3 += __shfl_xor(t3, 32);

    // logical columns for phys cols p0..p0+3:  c = ((p&7)<<4) + (p>>3)
    const int p0 = 4 * q;
    const int c0 = ((p0 & 7) << 4) + (p0 >> 3);
    const int c1 = (((p0 + 1) & 7) << 4) + ((p0 + 1) >> 3);
    const int c2 = (((p0 + 2) & 7) << 4) + ((p0 + 2) >> 3);
    const int c3 = (((p0 + 3) & 7) << 4) + ((p0 + 3) >> 3);

    // root + bias + relu
    t0 = fmaxf(t0 + __uint_as_float(vr.x << 16)         + bias[c0], 0.f);
    t1 = fmaxf(t1 + __uint_as_float(vr.x & 0xffff0000u) + bias[c1], 0.f);
    t2 = fmaxf(t2 + __uint_as_float(vr.y << 16)         + bias[c2], 0.f);
    t3 = fmaxf(t3 + __uint_as_float(vr.y & 0xffff0000u) + bias[c3], 0.f);

    if (mode == 1) {
        if (half == 0) {       // lanes 0-31 write the 256-B row (phys layout preserved)
            uint2 o;
            o.x = (unsigned)f2bf(t0) | ((unsigned)f2bf(t1) << 16);
            o.y = (unsigned)f2bf(t2) | ((unsigned)f2bf(t3) << 16);
            *(uint2*)((unsigned int*)outb + (size_t)node * 64 + 2 * q) = o;
        }
    } else {
        float s = t0 * Wc[c0] + t1 * Wc[c1] + t2 * Wc[c2] + t3 * Wc[c3];
        s += __shfl_xor(s, 1);
        s += __shfl_xor(s, 2);
        s += __shfl_xor(s, 4);
        s += __shfl_xor(s, 8);
        s += __shfl_xor(s, 16);
        if (lane == 0) outf[node] = s + bc[0];
    }
}

extern "C" void kernel_launch(void* const* d_in, const int* in_sizes, int n_in,
                              void* d_out, int out_size, void* d_ws, size_t ws_size,
                              hipStream_t stream) {
    const float* x     = (const float*)d_in[0];
    const int*   ei    = (const int*)d_in[1];
    const int*   et    = (const int*)d_in[2];
    const float* W1    = (const float*)d_in[3];
    const float* root1 = (const float*)d_in[4];
    const float* b1    = (const float*)d_in[5];
    const float* W2    = (const float*)d_in[6];
    const float* root2 = (const float*)d_in[7];
    const float* b2    = (const float*)d_in[8];
    const float* Wc    = (const float*)d_in[9];
    const float* bc    = (const float*)d_in[10];
    float* out = (float*)d_out;

    const int N = in_sizes[0] / Hd;
    const int E = in_sizes[2];
    const int* src  = ei;
    const int* dstp = ei + E;

    const size_t NH = (size_t)N * Hd;

    size_t off = 0;
    auto carve = [&](size_t bytes) -> char* {
        char* p = (char*)d_ws + off;
        off += (bytes + 255) & ~(size_t)255;
        return p;
    };
    unsigned short* xbf  = (unsigned short*)carve(NH * 2);            // also h (layer-2 A) after gather-1
    unsigned short* z    = (unsigned short*)carve((size_t)N * ZW * 2);
    unsigned short* Bt   = (unsigned short*)carve((size_t)2 * 9 * 16384 * 2);
    int*            deg  = (int*)carve((size_t)N * 4);
    int*            ovfc = (int*)carve(4);
    unsigned long long* ovf = (unsigned long long*)carve((size_t)E * 8);
    unsigned int*   epk  = (unsigned int*)carve((size_t)N * MAXDEG * 4);
    if (off > ws_size) return;

    // zero deg + ovfc in one memset (contiguous carves)
    size_t zspan = (size_t)((char*)ovfc - (char*)deg) + 256;
    hipMemsetAsync(deg, 0, zspan, stream);

    // merged prep: weight transpose + x cvt + edge placement
    const int n4 = (int)(NH / 4);
    const int eBlocks = (E + 255) / 256;
    prep_kernel<<<530 + eBlocks, 256, 0, stream>>>(x, xbf, n4, root1, W1, root2, W2, Bt,
                                                   src, dstp, et, E, deg, epk, ovf, ovfc);

    const int Mtiles = (N + 127) / 128;
    const int nodeBlocks = (N + 3) / 4;

    // layer 1: z = x @ [root1|W1...] (permuted cols), aggregate -> h (relu, bf16; aliased on xbf)
    gemm_z<<<Mtiles * 9, 256, 0, stream>>>(xbf, Bt, z, N);
    gather_out<<<nodeBlocks, 256, 0, stream>>>(z, deg, epk, ovf, ovfc, b1, nullptr, nullptr,
                                               xbf, nullptr, N, 1);
    // layer 2: z = h @ [root2|W2...] (K-permuted weights), aggregate + classifier -> out
    gemm_z<<<Mtiles * 9, 256, 0, stream>>>(xbf, Bt + (size_t)9 * 16384, z, N);
    gather_out<<<nodeBlocks, 256, 0, stream>>>(z, deg, epk, ovf, ovfc, b2, Wc, bc,
                                               nullptr, out, N, 2);
}